// Round 1
// baseline (2303.396 us; speedup 1.0000x reference)
//
#include <hip/hip_runtime.h>
#include <stdint.h>
#include <stddef.h>

typedef unsigned short u16t;
typedef unsigned int   u32t;
typedef __bf16  bf16x8 __attribute__((ext_vector_type(8)));
typedef float   f32x4  __attribute__((ext_vector_type(4)));

#define NN 50000
#define NE 800000
#define NG 16
#define DD 64
#define HH 128

#define HS 136   // h scratch row stride (u16): 128+8
#define ES 72    // e_new scratch row stride (u16): 64+8
#define EAS 72   // sEagg row stride (f32): 64+8 (spreads banks by g)
#define NS 136   // node A-tile stride (u16): 128+8

static __device__ __forceinline__ float bf2f(u16t h){
  return __uint_as_float(((u32t)h) << 16);
}
static __device__ __forceinline__ u16t f2bf(float f){
  u32t u = __float_as_uint(f);
  u32t r = u + 0x7FFFu + ((u >> 16) & 1u);   // RNE
  return (u16t)(r >> 16);
}
static __device__ __forceinline__ u32t pk2(float lo, float hi){
  return ((u32t)f2bf(hi) << 16) | (u32t)f2bf(lo);
}
static __device__ __forceinline__ bf16x8 ldfrag(const u16t* p){
  return __builtin_bit_cast(bf16x8, *(const uint4*)p);
}
// 8 consecutive f32 -> bf16x8 fragment
static __device__ __forceinline__ bf16x8 ldrowf(const float* p){
  float4 a = *(const float4*)p;
  float4 b = *(const float4*)(p + 4);
  uint4 o = { pk2(a.x, a.y), pk2(a.z, a.w), pk2(b.x, b.y), pk2(b.z, b.w) };
  return __builtin_bit_cast(bf16x8, o);
}
static __device__ __forceinline__ float ldb(const void* b, int i, bool f32){
  return f32 ? ((const float*)b)[i] : bf2f(((const u16t*)b)[i]);
}
static __device__ __forceinline__ void store1(void* out, size_t idx, float v, bool f32){
  if (f32) ((float*)out)[idx] = v;
  else     ((u16t*)out)[idx]  = f2bf(v);
}
// packed 16-element stage (2x ds_write_b128, no scalar b16 writes)
static __device__ __forceinline__ void stage16(u16t* dst, const void* src, size_t eoff, bool f32){
  if (!f32){
    const u16t* p = (const u16t*)src + eoff;
    *(uint4*)(dst)     = *(const uint4*)(p);
    *(uint4*)(dst + 8) = *(const uint4*)(p + 8);
  } else {
    const float* p = (const float*)src + eoff;
    float4 a = *(const float4*)(p);
    float4 b = *(const float4*)(p + 4);
    float4 c = *(const float4*)(p + 8);
    float4 d = *(const float4*)(p + 12);
    uint4 o0 = { pk2(a.x, a.y), pk2(a.z, a.w), pk2(b.x, b.y), pk2(b.z, b.w) };
    uint4 o1 = { pk2(c.x, c.y), pk2(c.z, c.w), pk2(d.x, d.y), pk2(d.z, d.w) };
    *(uint4*)(dst)     = o0;
    *(uint4*)(dst + 8) = o1;
  }
}
// within-wave LDS write->read visibility (no block barrier). Rule #18: sched_barrier after.
static __device__ __forceinline__ void wave_sync(){
  asm volatile("s_waitcnt lgkmcnt(0)" ::: "memory");
  __builtin_amdgcn_sched_barrier(0);
}

// Decide fp32 vs bf16 by interpreting x's first 256 u16 as bf16.
__global__ void detect_kernel(const void* x, int* flag){
  if (threadIdx.x == 0 && blockIdx.x == 0){
    const u16t* xh = (const u16t*)x;
    int bad = 0;
    for (int i = 0; i < 256; ++i){
      float a = fabsf(bf2f(xh[i]));
      if (!(a > 1e-6f && a < 1e4f)) bad++;
    }
    *flag = (bad > 32) ? 1 : 0;   // 1 = inputs are fp32
  }
}

// Repack W[K][Ncols] into MFMA-B-fragment order (bf16):
// Wp[((kk*Ncols + n)*32) + t] = W[kk*32 + t][n], t = quad*8 + j.
__global__ void repack_kernel(const void* __restrict__ W, u16t* __restrict__ Wp,
                              int K, int Ncols, const int* __restrict__ flag){
  const bool f32 = (*flag != 0);
  int idx = blockIdx.x * 256 + threadIdx.x;
  if (idx >= K * Ncols) return;
  int per = Ncols * 32;
  int kk  = idx / per;
  int rem = idx - kk * per;
  int n   = rem >> 5;
  int t   = rem & 31;
  int src = (kk * 32 + t) * Ncols + n;
  float v = f32 ? ((const float*)W)[src] : bf2f(((const u16t*)W)[src]);
  Wp[idx] = f2bf(v);
}

// Fold the u-part of each MLP-1 into a per-graph bias row (fp32, exact):
// U1[g][c]  = be1[c] + sum_k u[g][k]*We1[192+k][c]
// UA1[g][c] = ba1[c] + sum_k u[g][k]*Wa1[192+k][c]
// UN1[g][c] = bn1[c] + sum_k u[g][k]*Wn1[128+k][c]
__global__ void ufold_kernel(const void* __restrict__ u,
                             const void* __restrict__ We1, const void* __restrict__ be1,
                             const void* __restrict__ Wa1, const void* __restrict__ ba1,
                             const void* __restrict__ Wn1, const void* __restrict__ bn1,
                             float* __restrict__ U1, float* __restrict__ UA1,
                             float* __restrict__ UN1, const int* __restrict__ flag)
{
  const bool f32 = (*flag != 0);
  int idx = blockIdx.x * 256 + threadIdx.x;
  if (idx >= 3 * NG * HH) return;
  int which = idx / (NG * HH);
  int rem = idx - which * (NG * HH);
  int g = rem >> 7, c = rem & 127;
  const void* W; const void* b; int rowoff; float* out;
  if (which == 0)      { W = We1; b = be1; rowoff = 192; out = U1;  }
  else if (which == 1) { W = Wa1; b = ba1; rowoff = 192; out = UA1; }
  else                 { W = Wn1; b = bn1; rowoff = 128; out = UN1; }
  float sacc = ldb(b, c, f32);
  for (int k = 0; k < DD; ++k)
    sacc += ldb(u, g * DD + k, f32) * ldb(W, (rowoff + k) * HH + c, f32);
  out[rem] = sacc;
}

// One wave owns 16 edges end-to-end. A-fragments come straight from global
// (gather order == fragment order). LDS only holds wave-private h / e_new
// transpose scratch -> no __syncthreads in the main loop; wave_sync() only.
__global__ __launch_bounds__(256, 3) void edge_kernel(
  const void* __restrict__ x, const int* __restrict__ ei, const void* __restrict__ e,
  const int* __restrict__ batch,
  const u16t* __restrict__ Wp1, const u16t* __restrict__ WpA1,
  const u16t* __restrict__ Wp2, const void* __restrict__ b2,
  const u16t* __restrict__ WpA2, const void* __restrict__ ba2,
  const float* __restrict__ U1, const float* __restrict__ UA1,
  void* __restrict__ d_out, float* __restrict__ agg, float* __restrict__ edge_agg,
  const int* __restrict__ flag)
{
  __shared__ u16t  sH[4][16 * HS];   // per-wave h scratch
  __shared__ u16t  sE[4][16 * ES];   // per-wave e_new scratch
  __shared__ float sEagg[NG * EAS];

  const bool f32 = (*flag != 0);
  const size_t OUT_E = (size_t)NN * DD;

  const int tid  = threadIdx.x;
  const int wv   = tid >> 6;
  const int lane = tid & 63;
  const int l15  = lane & 15;
  const int quad = lane >> 4;

  for (int i = tid; i < NG * EAS; i += 256) sEagg[i] = 0.f;
  __syncthreads();   // once: sEagg zeroed before any wave's atomics

  u16t* const sHw = sH[wv];
  u16t* const sEw = sE[wv];

  // tile-invariant biases (layer-2 cols fixed per lane)
  float bias2[4], biasA2[4];
  #pragma unroll
  for (int c = 0; c < 4; ++c){
    bias2[c]  = ldb(b2,  c * 16 + l15, f32);
    biasA2[c] = ldb(ba2, c * 16 + l15, f32);
  }

  const f32x4 vzero = {0.f, 0.f, 0.f, 0.f};
  const int NT = NE / 16;

  for (int t = blockIdx.x * 4 + wv; t < NT; t += gridDim.x * 4){
    const int e0 = t * 16;
    const int s  = ei[e0 + l15];
    const int d  = ei[NE + e0 + l15];
    const int g  = batch[s];
    int gr[4], dr[4];
    #pragma unroll
    for (int r = 0; r < 4; ++r){
      gr[r] = __shfl(g, quad * 4 + r);   // graph of C-row quad*4+r
      dr[r] = __shfl(d, quad * 4 + r);   // dst   of C-row quad*4+r
    }
    const size_t oxs = (size_t)s * DD;
    const size_t oxd = (size_t)d * DD;
    const size_t oe  = (size_t)(e0 + l15) * DD;

    // ---- layer 1 (K=192): edge full + attention [xs|xd] partial, shared A ----
    f32x4 accE[8], accA[8];
    #pragma unroll
    for (int i = 0; i < 8; ++i){ accE[i] = vzero; accA[i] = vzero; }

    #pragma unroll
    for (int kk = 0; kk < 6; ++kk){
      bf16x8 af;
      const int koff = (kk & 1) * 32 + quad * 8;
      if (f32){
        const float* base = (kk < 2) ? ((const float*)x + oxs)
                          : (kk < 4) ? ((const float*)x + oxd)
                                     : ((const float*)e + oe);
        af = ldrowf(base + koff);
      } else {
        const u16t* base = (kk < 2) ? ((const u16t*)x + oxs)
                         : (kk < 4) ? ((const u16t*)x + oxd)
                                    : ((const u16t*)e + oe);
        af = ldfrag(base + koff);
      }
      const u16t* w1k = Wp1 + ((kk * HH + l15) << 5) + quad * 8;
      #pragma unroll
      for (int ct = 0; ct < 8; ++ct)
        accE[ct] = __builtin_amdgcn_mfma_f32_16x16x32_bf16(af, ldfrag(w1k + (ct << 9)), accE[ct], 0, 0, 0);
      if (kk < 4){
        const u16t* wak = WpA1 + ((kk * HH + l15) << 5) + quad * 8;
        #pragma unroll
        for (int ct = 0; ct < 8; ++ct)
          accA[ct] = __builtin_amdgcn_mfma_f32_16x16x32_bf16(af, ldfrag(wak + (ct << 9)), accA[ct], 0, 0, 0);
      }
    }

    // h = relu(accE + U1[g])  -> wave-private sH
    #pragma unroll
    for (int ct = 0; ct < 8; ++ct){
      const int col = ct * 16 + l15;
      #pragma unroll
      for (int r = 0; r < 4; ++r){
        float hv = accE[ct][r] + U1[gr[r] * HH + col];
        sHw[(quad * 4 + r) * HS + col] = f2bf(fmaxf(hv, 0.f));
      }
    }
    wave_sync();

    // ---- edge layer 2 (K=128) -> e_new ----
    f32x4 acc2[4];
    #pragma unroll
    for (int i = 0; i < 4; ++i) acc2[i] = vzero;
    #pragma unroll
    for (int kk = 0; kk < 4; ++kk){
      bf16x8 af = ldfrag(&sHw[l15 * HS + kk * 32 + quad * 8]);
      const u16t* w2k = Wp2 + ((kk * DD + l15) << 5) + quad * 8;
      #pragma unroll
      for (int c = 0; c < 4; ++c)
        acc2[c] = __builtin_amdgcn_mfma_f32_16x16x32_bf16(af, ldfrag(w2k + (c << 9)), acc2[c], 0, 0, 0);
    }
    float enew[4][4];
    #pragma unroll
    for (int c = 0; c < 4; ++c){
      const int col = c * 16 + l15;
      #pragma unroll
      for (int r = 0; r < 4; ++r){
        float v = acc2[c][r] + bias2[c];
        enew[c][r] = v;
        const int row = quad * 4 + r;
        store1(d_out, OUT_E + (size_t)(e0 + row) * DD + col, v, f32);
        sEw[row * ES + col] = f2bf(v);
        atomicAdd(&sEagg[gr[r] * EAS + col], v);
      }
    }
    wave_sync();

    // ---- attention finish: + e_new @ Wa1[128:192] ----
    #pragma unroll
    for (int kkl = 0; kkl < 2; ++kkl){
      bf16x8 af = ldfrag(&sEw[l15 * ES + kkl * 32 + quad * 8]);
      const u16t* wak = WpA1 + (((4 + kkl) * HH + l15) << 5) + quad * 8;
      #pragma unroll
      for (int ct = 0; ct < 8; ++ct)
        accA[ct] = __builtin_amdgcn_mfma_f32_16x16x32_bf16(af, ldfrag(wak + (ct << 9)), accA[ct], 0, 0, 0);
    }
    #pragma unroll
    for (int ct = 0; ct < 8; ++ct){
      const int col = ct * 16 + l15;
      #pragma unroll
      for (int r = 0; r < 4; ++r){
        float hv = accA[ct][r] + UA1[gr[r] * HH + col];
        sHw[(quad * 4 + r) * HS + col] = f2bf(fmaxf(hv, 0.f));
      }
    }
    wave_sync();

    // ---- attention layer 2 -> sigmoid -> scatter e_new*a into agg[dst] ----
    f32x4 acc4[4];
    #pragma unroll
    for (int i = 0; i < 4; ++i) acc4[i] = vzero;
    #pragma unroll
    for (int kk = 0; kk < 4; ++kk){
      bf16x8 af = ldfrag(&sHw[l15 * HS + kk * 32 + quad * 8]);
      const u16t* w4k = WpA2 + ((kk * DD + l15) << 5) + quad * 8;
      #pragma unroll
      for (int c = 0; c < 4; ++c)
        acc4[c] = __builtin_amdgcn_mfma_f32_16x16x32_bf16(af, ldfrag(w4k + (c << 9)), acc4[c], 0, 0, 0);
    }
    #pragma unroll
    for (int c = 0; c < 4; ++c){
      const int col = c * 16 + l15;
      #pragma unroll
      for (int r = 0; r < 4; ++r){
        float sv = acc4[c][r] + biasA2[c];
        float av = 1.0f / (1.0f + __expf(-sv));
        atomicAdd(&agg[(size_t)dr[r] * DD + col], enew[c][r] * av);
      }
    }
  }

  __syncthreads();
  for (int i = tid; i < NG * DD; i += 256)
    atomicAdd(&edge_agg[i], sEagg[(i >> 6) * EAS + (i & 63)]);
}

__global__ __launch_bounds__(256) void node_kernel(
  const void* __restrict__ x, const float* __restrict__ agg,
  const int* __restrict__ batch,
  const u16t* __restrict__ WpN1, const float* __restrict__ UN1,
  const u16t* __restrict__ WpN2, const void* __restrict__ bn2,
  void* __restrict__ d_out, float* __restrict__ node_agg, const int* __restrict__ flag)
{
  __shared__ u16t  sA[64 * NS];
  __shared__ u16t  sH[64 * HS];
  __shared__ float sNagg[NG * 72];
  __shared__ int   sGn[64];

  const bool f32 = (*flag != 0);
  const int tid  = threadIdx.x;
  const int wave = tid >> 6;
  const int lane = tid & 63;
  const int l15  = lane & 15;
  const int quad = lane >> 4;
  const int base = blockIdx.x * 64;

  for (int i = tid; i < NG * 72; i += 256) sNagg[i] = 0.f;

  // ---- stage [x | agg], 64 x 128 bf16 (u folded into UN1) ----
  {
    const int el = tid >> 2;
    const int q  = tid & 3;
    int n  = base + el;
    int nc = n < NN ? n : (NN - 1);
    int g  = batch[nc];
    if (q == 0) sGn[el] = g;
    u16t* row = sA + el * NS + q * 16;
    stage16(row,      x,   (size_t)nc * DD + q * 16, f32);
    stage16(row + 64, agg, (size_t)nc * DD + q * 16, true);
  }
  __syncthreads();

  const f32x4 vzero = {0.f, 0.f, 0.f, 0.f};
  const int colbase = wave * 32;
  const int n0      = wave * 16;

  // ---- node MLP layer 1: K=128 ----
  f32x4 acc[4][2];
  #pragma unroll
  for (int rt = 0; rt < 4; ++rt){ acc[rt][0] = vzero; acc[rt][1] = vzero; }
  #pragma unroll
  for (int kk = 0; kk < 4; ++kk){
    bf16x8 af[4], bw[2];
    #pragma unroll
    for (int rt = 0; rt < 4; ++rt)
      af[rt] = ldfrag(&sA[(rt * 16 + l15) * NS + kk * 32 + quad * 8]);
    #pragma unroll
    for (int ct = 0; ct < 2; ++ct)
      bw[ct] = ldfrag(&WpN1[((kk * HH + colbase + ct * 16 + l15) << 5) + quad * 8]);
    #pragma unroll
    for (int rt = 0; rt < 4; ++rt)
      #pragma unroll
      for (int ct = 0; ct < 2; ++ct)
        acc[rt][ct] = __builtin_amdgcn_mfma_f32_16x16x32_bf16(af[rt], bw[ct], acc[rt][ct], 0, 0, 0);
  }
  #pragma unroll
  for (int ct = 0; ct < 2; ++ct){
    const int col = colbase + ct * 16 + l15;
    #pragma unroll
    for (int rt = 0; rt < 4; ++rt)
      #pragma unroll
      for (int r = 0; r < 4; ++r){
        const int row = rt * 16 + quad * 4 + r;
        float h = fmaxf(acc[rt][ct][r] + UN1[sGn[row] * HH + col], 0.f);
        sH[row * HS + col] = f2bf(h);
      }
  }
  __syncthreads();

  // ---- node MLP layer 2 -> x_new ----
  f32x4 acc2[4];
  #pragma unroll
  for (int rt = 0; rt < 4; ++rt) acc2[rt] = vzero;
  #pragma unroll
  for (int kk = 0; kk < 4; ++kk){
    bf16x8 af[4];
    #pragma unroll
    for (int rt = 0; rt < 4; ++rt)
      af[rt] = ldfrag(&sH[(rt * 16 + l15) * HS + kk * 32 + quad * 8]);
    bf16x8 bw = ldfrag(&WpN2[((kk * 64 + n0 + l15) << 5) + quad * 8]);
    #pragma unroll
    for (int rt = 0; rt < 4; ++rt)
      acc2[rt] = __builtin_amdgcn_mfma_f32_16x16x32_bf16(af[rt], bw, acc2[rt], 0, 0, 0);
  }
  {
    const int col = n0 + l15;
    const float bias = ldb(bn2, col, f32);
    #pragma unroll
    for (int rt = 0; rt < 4; ++rt)
      #pragma unroll
      for (int r = 0; r < 4; ++r){
        const int row = rt * 16 + quad * 4 + r;
        const int n = base + row;
        if (n < NN){
          float v = acc2[rt][r] + bias;
          store1(d_out, (size_t)n * DD + col, v, f32);
          atomicAdd(&sNagg[sGn[row] * 72 + col], v);
        }
      }
  }
  __syncthreads();
  for (int i = tid; i < NG * DD; i += 256)
    atomicAdd(&node_agg[i], sNagg[(i >> 6) * 72 + (i & 63)]);
}

__global__ __launch_bounds__(256) void global_kernel(
  const void* __restrict__ u, const float* __restrict__ node_agg, const float* __restrict__ edge_agg,
  const void* __restrict__ Wg1, const void* __restrict__ bg1,
  const void* __restrict__ Wg2, const void* __restrict__ bg2,
  void* __restrict__ d_out, const int* __restrict__ flag)
{
  __shared__ float sIn[NG * 192];
  __shared__ float sHg[NG * HH];
  const bool f32 = (*flag != 0);
  const size_t OUT_U = (size_t)NN * DD + (size_t)NE * DD;
  const int tid = threadIdx.x;
  for (int i = tid; i < NG * 192; i += 256){
    int g = i / 192, c = i - g * 192;
    float v;
    if      (c <  64) v = ldb(u, g * 64 + c, f32);
    else if (c < 128) v = node_agg[g * 64 + (c - 64)];
    else              v = edge_agg[g * 64 + (c - 128)];
    sIn[i] = v;
  }
  __syncthreads();
  for (int i = tid; i < NG * HH; i += 256){
    int g = i >> 7, j = i & 127;
    float s = ldb(bg1, j, f32);
    for (int k = 0; k < 192; ++k)
      s += sIn[g * 192 + k] * ldb(Wg1, k * 128 + j, f32);
    sHg[i] = fmaxf(s, 0.f);
  }
  __syncthreads();
  for (int i = tid; i < NG * DD; i += 256){
    int g = i >> 6, j = i & 63;
    float s = ldb(bg2, j, f32);
    for (int k = 0; k < 128; ++k)
      s += sHg[g * 128 + k] * ldb(Wg2, k * 64 + j, f32);
    store1(d_out, OUT_U + i, s, f32);
  }
}

extern "C" void kernel_launch(void* const* d_in, const int* in_sizes, int n_in,
                              void* d_out, int out_size, void* d_ws, size_t ws_size,
                              hipStream_t stream)
{
  const void* x     = d_in[0];
  const int*  ei    = (const int*)d_in[1];
  const void* e     = d_in[2];
  const void* u     = d_in[3];
  const int*  batch = (const int*)d_in[4];
  const void* We1 = d_in[5];
  const void* be1 = d_in[6];
  const void* We2 = d_in[7];
  const void* be2 = d_in[8];
  const void* Wa1 = d_in[9];
  const void* ba1 = d_in[10];
  const void* Wa2 = d_in[11];
  const void* ba2 = d_in[12];
  const void* Wn1 = d_in[13];
  const void* bn1 = d_in[14];
  const void* Wn2 = d_in[15];
  const void* bn2 = d_in[16];
  const void* Wg1 = d_in[17];
  const void* bg1 = d_in[18];
  const void* Wg2 = d_in[19];
  const void* bg2 = d_in[20];

  // workspace: [flag 16B][agg NN*DD][edge_agg][node_agg][U1][UA1][UN1][packed W]
  int*   flag     = (int*)d_ws;
  float* agg      = (float*)((char*)d_ws + 16);
  float* edge_agg = agg + (size_t)NN * DD;
  float* node_agg = edge_agg + NG * DD;
  float* U1  = node_agg + NG * DD;
  float* UA1 = U1  + NG * HH;
  float* UN1 = UA1 + NG * HH;
  u16t*  wp    = (u16t*)(UN1 + NG * HH);
  u16t*  Wp_e1 = wp; wp += 256 * 128;
  u16t*  Wp_e2 = wp; wp += 128 * 64;
  u16t*  Wp_a1 = wp; wp += 256 * 128;
  u16t*  Wp_a2 = wp; wp += 128 * 64;
  u16t*  Wp_n1 = wp; wp += 192 * 128;
  u16t*  Wp_n2 = wp; wp += 128 * 64;

  detect_kernel<<<1, 64, 0, stream>>>(x, flag);
  hipMemsetAsync(agg, 0, ((size_t)NN * DD + 2 * NG * DD) * sizeof(float), stream);

  ufold_kernel<<<(3 * NG * HH + 255) / 256, 256, 0, stream>>>(
      u, We1, be1, Wa1, ba1, Wn1, bn1, U1, UA1, UN1, flag);

  repack_kernel<<<(192 * 128 + 255) / 256, 256, 0, stream>>>(We1, Wp_e1, 192, 128, flag);
  repack_kernel<<<(128 * 64  + 255) / 256, 256, 0, stream>>>(We2, Wp_e2, 128, 64, flag);
  repack_kernel<<<(192 * 128 + 255) / 256, 256, 0, stream>>>(Wa1, Wp_a1, 192, 128, flag);
  repack_kernel<<<(128 * 64  + 255) / 256, 256, 0, stream>>>(Wa2, Wp_a2, 128, 64, flag);
  repack_kernel<<<(128 * 128 + 255) / 256, 256, 0, stream>>>(Wn1, Wp_n1, 128, 128, flag);
  repack_kernel<<<(128 * 64  + 255) / 256, 256, 0, stream>>>(Wn2, Wp_n2, 128, 64, flag);

  edge_kernel<<<1536, 256, 0, stream>>>(x, ei, e, batch,
      Wp_e1, Wp_a1, Wp_e2, be2, Wp_a2, ba2, U1, UA1,
      d_out, agg, edge_agg, flag);

  node_kernel<<<(NN + 63) / 64, 256, 0, stream>>>(x, agg, batch,
      Wp_n1, UN1, Wp_n2, bn2, d_out, node_agg, flag);

  global_kernel<<<1, 256, 0, stream>>>(u, node_agg, edge_agg,
      Wg1, bg1, Wg2, bg2, d_out, flag);
}

// Round 2
// 1161.515 us; speedup vs baseline: 1.9831x; 1.9831x over previous
//
#include <hip/hip_runtime.h>
#include <stdint.h>
#include <stddef.h>

typedef unsigned short u16t;
typedef unsigned int   u32t;
typedef __bf16  bf16x8 __attribute__((ext_vector_type(8)));
typedef float   f32x4  __attribute__((ext_vector_type(4)));

#define NN 50000
#define NE 800000
#define NG 16
#define DD 64
#define HH 128

#define AS 200   // edge A-tile row stride (u16): 192 + 8 pad -> 2-way bank alias (free)
#define HS 136   // h-tile row stride (u16): 128 + 8
#define EAS 72   // sEagg row stride (f32)
#define NS 136   // node A-tile row stride (u16): 128 + 8

static __device__ __forceinline__ float bf2f(u16t h){
  return __uint_as_float(((u32t)h) << 16);
}
static __device__ __forceinline__ u16t f2bf(float f){
  u32t u = __float_as_uint(f);
  u32t r = u + 0x7FFFu + ((u >> 16) & 1u);   // RNE
  return (u16t)(r >> 16);
}
static __device__ __forceinline__ u32t pk2(float lo, float hi){
  return ((u32t)f2bf(hi) << 16) | (u32t)f2bf(lo);
}
static __device__ __forceinline__ bf16x8 ldfrag(const u16t* p){
  return __builtin_bit_cast(bf16x8, *(const uint4*)p);
}
static __device__ __forceinline__ float ldb(const void* b, int i, bool f32){
  return f32 ? ((const float*)b)[i] : bf2f(((const u16t*)b)[i]);
}
static __device__ __forceinline__ void store1(void* out, size_t idx, float v, bool f32){
  if (f32) ((float*)out)[idx] = v;
  else     ((u16t*)out)[idx]  = f2bf(v);
}
// stage 16 consecutive logical elements -> 16 bf16 in LDS via 2x ds_write_b128
static __device__ __forceinline__ void stage16(u16t* dst, const void* src, size_t eoff, bool f32){
  if (!f32){
    const u16t* p = (const u16t*)src + eoff;
    *(uint4*)(dst)     = *(const uint4*)(p);
    *(uint4*)(dst + 8) = *(const uint4*)(p + 8);
  } else {
    const float* p = (const float*)src + eoff;
    float4 a = *(const float4*)(p);
    float4 b = *(const float4*)(p + 4);
    float4 c = *(const float4*)(p + 8);
    float4 d = *(const float4*)(p + 12);
    uint4 o0 = { pk2(a.x, a.y), pk2(a.z, a.w), pk2(b.x, b.y), pk2(b.z, b.w) };
    uint4 o1 = { pk2(c.x, c.y), pk2(c.z, c.w), pk2(d.x, d.y), pk2(d.z, d.w) };
    *(uint4*)(dst)     = o0;
    *(uint4*)(dst + 8) = o1;
  }
}

// Decide fp32 vs bf16 by interpreting x's first 256 u16 as bf16.
__global__ void detect_kernel(const void* x, int* flag){
  if (threadIdx.x == 0 && blockIdx.x == 0){
    const u16t* xh = (const u16t*)x;
    int bad = 0;
    for (int i = 0; i < 256; ++i){
      float a = fabsf(bf2f(xh[i]));
      if (!(a > 1e-6f && a < 1e4f)) bad++;
    }
    *flag = (bad > 32) ? 1 : 0;   // 1 = inputs are fp32
  }
}

// Repack W[K][Ncols] into MFMA-B-fragment order (bf16):
// Wp[((kk*Ncols + n)*32) + t] = W[kk*32 + t][n], t = quad*8 + j.
__global__ void repack_kernel(const void* __restrict__ W, u16t* __restrict__ Wp,
                              int K, int Ncols, const int* __restrict__ flag){
  const bool f32 = (*flag != 0);
  int idx = blockIdx.x * 256 + threadIdx.x;
  if (idx >= K * Ncols) return;
  int per = Ncols * 32;
  int kk  = idx / per;
  int rem = idx - kk * per;
  int n   = rem >> 5;
  int t   = rem & 31;
  int src = (kk * 32 + t) * Ncols + n;
  float v = f32 ? ((const float*)W)[src] : bf2f(((const u16t*)W)[src]);
  Wp[idx] = f2bf(v);
}

// Fold the u-part of each MLP-1 into a per-graph bias row (fp32, exact):
// U1[g][c]  = be1[c] + sum_k u[g][k]*We1[192+k][c]
// UA1[g][c] = ba1[c] + sum_k u[g][k]*Wa1[192+k][c]
// UN1[g][c] = bn1[c] + sum_k u[g][k]*Wn1[128+k][c]
__global__ void ufold_kernel(const void* __restrict__ u,
                             const void* __restrict__ We1, const void* __restrict__ be1,
                             const void* __restrict__ Wa1, const void* __restrict__ ba1,
                             const void* __restrict__ Wn1, const void* __restrict__ bn1,
                             float* __restrict__ U1, float* __restrict__ UA1,
                             float* __restrict__ UN1, const int* __restrict__ flag)
{
  const bool f32 = (*flag != 0);
  int idx = blockIdx.x * 256 + threadIdx.x;
  if (idx >= 3 * NG * HH) return;
  int which = idx / (NG * HH);
  int rem = idx - which * (NG * HH);
  int g = rem >> 7, c = rem & 127;
  const void* W; const void* b; int rowoff; float* out;
  if (which == 0)      { W = We1; b = be1; rowoff = 192; out = U1;  }
  else if (which == 1) { W = Wa1; b = ba1; rowoff = 192; out = UA1; }
  else                 { W = Wn1; b = bn1; rowoff = 128; out = UN1; }
  float sacc = ldb(b, c, f32);
  for (int k = 0; k < DD; ++k)
    sacc += ldb(u, g * DD + k, f32) * ldb(W, (rowoff + k) * HH + c, f32);
  out[rem] = sacc;
}

// Block-wide 64-edge tiles (proven FETCH-floor structure). Per-wave column
// slices of weights (8:1 MFMA:load). u folded into U1/UA1. Edge-L1 and
// attn-L1 share one pass over the staged A-tile.
__global__ __launch_bounds__(256, 3) void edge_kernel(
  const void* __restrict__ x, const int* __restrict__ ei, const void* __restrict__ e,
  const int* __restrict__ batch,
  const u16t* __restrict__ Wp1, const u16t* __restrict__ WpA1,
  const u16t* __restrict__ Wp2, const void* __restrict__ b2,
  const u16t* __restrict__ WpA2, const void* __restrict__ ba2,
  const float* __restrict__ U1, const float* __restrict__ UA1,
  void* __restrict__ d_out, float* __restrict__ agg, float* __restrict__ edge_agg,
  const int* __restrict__ flag, int ntiles)
{
  __shared__ u16t  sA[64 * AS];       // [xs | xd | e] 64 x 192
  __shared__ u16t  sH[64 * HS];
  __shared__ float sEagg[NG * EAS];
  __shared__ int   sDst[64];
  __shared__ int   sG[64];

  const bool f32 = (*flag != 0);
  const size_t OUT_E = (size_t)NN * DD;

  const int tid  = threadIdx.x;
  const int wave = tid >> 6;
  const int lane = tid & 63;
  const int l15  = lane & 15;
  const int quad = lane >> 4;
  const int el   = tid >> 2;   // local edge 0..63 (4 threads/edge)
  const int q    = tid & 3;    // 16-col chunk within D=64

  for (int i = tid; i < NG * EAS; i += 256) sEagg[i] = 0.f;

  const int colbase = wave * 32;  // layer-1 col range per wave
  const int n0      = wave * 16;  // layer-2 col range per wave
  const float bias2  = ldb(b2,  n0 + l15, f32);
  const float biasA2 = ldb(ba2, n0 + l15, f32);

  const f32x4 vzero = {0.f, 0.f, 0.f, 0.f};

  for (int tile = blockIdx.x; tile < ntiles; tile += gridDim.x){
    const int base = tile * 64;

    // ---- stage input tile [xs | xd | e], bf16, 64 x 192 ----
    {
      const int eidx = base + el;
      const int s = ei[eidx];
      const int d = ei[NE + eidx];
      if (q == 0) sDst[el] = d;
      if (q == 1) sG[el]   = batch[ei[eidx]];
      u16t* row = sA + el * AS + q * 16;
      stage16(row +   0, x, (size_t)s    * DD + q * 16, f32);
      stage16(row +  64, x, (size_t)d    * DD + q * 16, f32);
      stage16(row + 128, e, (size_t)eidx * DD + q * 16, f32);
    }
    __syncthreads();

    // ---- fused layer 1 (K=192): edge full + attention [xs|xd|.] partial ----
    f32x4 accE[4][2], accA[4][2];
    #pragma unroll
    for (int rt = 0; rt < 4; ++rt){
      accE[rt][0] = vzero; accE[rt][1] = vzero;
      accA[rt][0] = vzero; accA[rt][1] = vzero;
    }
    #pragma unroll
    for (int kk = 0; kk < 6; ++kk){
      bf16x8 af[4], bwE[2];
      #pragma unroll
      for (int rt = 0; rt < 4; ++rt)
        af[rt] = ldfrag(&sA[(rt * 16 + l15) * AS + kk * 32 + quad * 8]);
      #pragma unroll
      for (int ct = 0; ct < 2; ++ct)
        bwE[ct] = ldfrag(&Wp1[((kk * HH + colbase + ct * 16 + l15) << 5) + quad * 8]);
      #pragma unroll
      for (int rt = 0; rt < 4; ++rt)
        #pragma unroll
        for (int ct = 0; ct < 2; ++ct)
          accE[rt][ct] = __builtin_amdgcn_mfma_f32_16x16x32_bf16(af[rt], bwE[ct], accE[rt][ct], 0, 0, 0);
      if (kk < 4){
        bf16x8 bwA[2];
        #pragma unroll
        for (int ct = 0; ct < 2; ++ct)
          bwA[ct] = ldfrag(&WpA1[((kk * HH + colbase + ct * 16 + l15) << 5) + quad * 8]);
        #pragma unroll
        for (int rt = 0; rt < 4; ++rt)
          #pragma unroll
          for (int ct = 0; ct < 2; ++ct)
            accA[rt][ct] = __builtin_amdgcn_mfma_f32_16x16x32_bf16(af[rt], bwA[ct], accA[rt][ct], 0, 0, 0);
      }
    }
    #pragma unroll
    for (int ct = 0; ct < 2; ++ct){
      const int col = colbase + ct * 16 + l15;
      #pragma unroll
      for (int rt = 0; rt < 4; ++rt)
        #pragma unroll
        for (int r = 0; r < 4; ++r){
          const int row = rt * 16 + quad * 4 + r;
          float h = fmaxf(accE[rt][ct][r] + U1[sG[row] * HH + col], 0.f);
          sH[row * HS + col] = f2bf(h);
        }
    }
    __syncthreads();

    // ---- edge MLP layer 2: [64x128] @ [128x64] -> e_new ----
    f32x4 acc2[4];
    #pragma unroll
    for (int rt = 0; rt < 4; ++rt) acc2[rt] = vzero;
    #pragma unroll
    for (int kk = 0; kk < 4; ++kk){
      bf16x8 af[4];
      #pragma unroll
      for (int rt = 0; rt < 4; ++rt)
        af[rt] = ldfrag(&sH[(rt * 16 + l15) * HS + kk * 32 + quad * 8]);
      bf16x8 bw = ldfrag(&Wp2[((kk * 64 + n0 + l15) << 5) + quad * 8]);
      #pragma unroll
      for (int rt = 0; rt < 4; ++rt)
        acc2[rt] = __builtin_amdgcn_mfma_f32_16x16x32_bf16(af[rt], bw, acc2[rt], 0, 0, 0);
    }
    float enew[4][4];
    {
      const int col = n0 + l15;
      #pragma unroll
      for (int rt = 0; rt < 4; ++rt)
        #pragma unroll
        for (int r = 0; r < 4; ++r){
          float v = acc2[rt][r] + bias2;
          enew[rt][r] = v;
          const int row = rt * 16 + quad * 4 + r;
          store1(d_out, OUT_E + (size_t)(base + row) * DD + col, v, f32);
          sA[row * AS + 128 + col] = f2bf(v);   // e-slot <- e_new for attention
          atomicAdd(&sEagg[sG[row] * EAS + col], v);
        }
    }
    __syncthreads();

    // ---- attention finish: + e_new @ Wa1[128:192] rows ----
    #pragma unroll
    for (int kkl = 0; kkl < 2; ++kkl){
      bf16x8 af[4], bwA[2];
      #pragma unroll
      for (int rt = 0; rt < 4; ++rt)
        af[rt] = ldfrag(&sA[(rt * 16 + l15) * AS + 128 + kkl * 32 + quad * 8]);
      #pragma unroll
      for (int ct = 0; ct < 2; ++ct)
        bwA[ct] = ldfrag(&WpA1[(((4 + kkl) * HH + colbase + ct * 16 + l15) << 5) + quad * 8]);
      #pragma unroll
      for (int rt = 0; rt < 4; ++rt)
        #pragma unroll
        for (int ct = 0; ct < 2; ++ct)
          accA[rt][ct] = __builtin_amdgcn_mfma_f32_16x16x32_bf16(af[rt], bwA[ct], accA[rt][ct], 0, 0, 0);
    }
    #pragma unroll
    for (int ct = 0; ct < 2; ++ct){
      const int col = colbase + ct * 16 + l15;
      #pragma unroll
      for (int rt = 0; rt < 4; ++rt)
        #pragma unroll
        for (int r = 0; r < 4; ++r){
          const int row = rt * 16 + quad * 4 + r;
          float h = fmaxf(accA[rt][ct][r] + UA1[sG[row] * HH + col], 0.f);
          sH[row * HS + col] = f2bf(h);
        }
    }
    __syncthreads();

    // ---- attention layer 2 -> sigmoid -> scatter e_new*a into agg[dst] ----
    f32x4 acc4[4];
    #pragma unroll
    for (int rt = 0; rt < 4; ++rt) acc4[rt] = vzero;
    #pragma unroll
    for (int kk = 0; kk < 4; ++kk){
      bf16x8 af[4];
      #pragma unroll
      for (int rt = 0; rt < 4; ++rt)
        af[rt] = ldfrag(&sH[(rt * 16 + l15) * HS + kk * 32 + quad * 8]);
      bf16x8 bw = ldfrag(&WpA2[((kk * 64 + n0 + l15) << 5) + quad * 8]);
      #pragma unroll
      for (int rt = 0; rt < 4; ++rt)
        acc4[rt] = __builtin_amdgcn_mfma_f32_16x16x32_bf16(af[rt], bw, acc4[rt], 0, 0, 0);
    }
    {
      const int col = n0 + l15;
      #pragma unroll
      for (int rt = 0; rt < 4; ++rt)
        #pragma unroll
        for (int r = 0; r < 4; ++r){
          float sv = acc4[rt][r] + biasA2;
          float av = 1.0f / (1.0f + __expf(-sv));
          const int row = rt * 16 + quad * 4 + r;
          atomicAdd(&agg[(size_t)sDst[row] * DD + col], enew[rt][r] * av);
        }
    }
    __syncthreads();   // protect sA/sH/sDst/sG before next tile's staging
  }

  // flush per-block edge_agg partial
  for (int i = tid; i < NG * DD; i += 256)
    atomicAdd(&edge_agg[i], sEagg[(i >> 6) * EAS + (i & 63)]);
}

__global__ __launch_bounds__(256) void node_kernel(
  const void* __restrict__ x, const float* __restrict__ agg,
  const int* __restrict__ batch,
  const u16t* __restrict__ WpN1, const float* __restrict__ UN1,
  const u16t* __restrict__ WpN2, const void* __restrict__ bn2,
  void* __restrict__ d_out, float* __restrict__ node_agg, const int* __restrict__ flag)
{
  __shared__ u16t  sA[64 * NS];
  __shared__ u16t  sH[64 * HS];
  __shared__ float sNagg[NG * 72];
  __shared__ int   sGn[64];

  const bool f32 = (*flag != 0);
  const int tid  = threadIdx.x;
  const int wave = tid >> 6;
  const int lane = tid & 63;
  const int l15  = lane & 15;
  const int quad = lane >> 4;
  const int base = blockIdx.x * 64;

  for (int i = tid; i < NG * 72; i += 256) sNagg[i] = 0.f;

  // ---- stage [x | agg], 64 x 128 bf16 (u folded into UN1) ----
  {
    const int el = tid >> 2;
    const int q  = tid & 3;
    int n  = base + el;
    int nc = n < NN ? n : (NN - 1);
    int g  = batch[nc];
    if (q == 0) sGn[el] = g;
    u16t* row = sA + el * NS + q * 16;
    stage16(row,      x,   (size_t)nc * DD + q * 16, f32);
    stage16(row + 64, agg, (size_t)nc * DD + q * 16, true);
  }
  __syncthreads();

  const f32x4 vzero = {0.f, 0.f, 0.f, 0.f};
  const int colbase = wave * 32;
  const int n0      = wave * 16;

  // ---- node MLP layer 1: K=128 ----
  f32x4 acc[4][2];
  #pragma unroll
  for (int rt = 0; rt < 4; ++rt){ acc[rt][0] = vzero; acc[rt][1] = vzero; }
  #pragma unroll
  for (int kk = 0; kk < 4; ++kk){
    bf16x8 af[4], bw[2];
    #pragma unroll
    for (int rt = 0; rt < 4; ++rt)
      af[rt] = ldfrag(&sA[(rt * 16 + l15) * NS + kk * 32 + quad * 8]);
    #pragma unroll
    for (int ct = 0; ct < 2; ++ct)
      bw[ct] = ldfrag(&WpN1[((kk * HH + colbase + ct * 16 + l15) << 5) + quad * 8]);
    #pragma unroll
    for (int rt = 0; rt < 4; ++rt)
      #pragma unroll
      for (int ct = 0; ct < 2; ++ct)
        acc[rt][ct] = __builtin_amdgcn_mfma_f32_16x16x32_bf16(af[rt], bw[ct], acc[rt][ct], 0, 0, 0);
  }
  #pragma unroll
  for (int ct = 0; ct < 2; ++ct){
    const int col = colbase + ct * 16 + l15;
    #pragma unroll
    for (int rt = 0; rt < 4; ++rt)
      #pragma unroll
      for (int r = 0; r < 4; ++r){
        const int row = rt * 16 + quad * 4 + r;
        float h = fmaxf(acc[rt][ct][r] + UN1[sGn[row] * HH + col], 0.f);
        sH[row * HS + col] = f2bf(h);
      }
  }
  __syncthreads();

  // ---- node MLP layer 2 -> x_new ----
  f32x4 acc2[4];
  #pragma unroll
  for (int rt = 0; rt < 4; ++rt) acc2[rt] = vzero;
  #pragma unroll
  for (int kk = 0; kk < 4; ++kk){
    bf16x8 af[4];
    #pragma unroll
    for (int rt = 0; rt < 4; ++rt)
      af[rt] = ldfrag(&sH[(rt * 16 + l15) * HS + kk * 32 + quad * 8]);
    bf16x8 bw = ldfrag(&WpN2[((kk * 64 + n0 + l15) << 5) + quad * 8]);
    #pragma unroll
    for (int rt = 0; rt < 4; ++rt)
      acc2[rt] = __builtin_amdgcn_mfma_f32_16x16x32_bf16(af[rt], bw, acc2[rt], 0, 0, 0);
  }
  {
    const int col = n0 + l15;
    const float bias = ldb(bn2, col, f32);
    #pragma unroll
    for (int rt = 0; rt < 4; ++rt)
      #pragma unroll
      for (int r = 0; r < 4; ++r){
        const int row = rt * 16 + quad * 4 + r;
        const int n = base + row;
        if (n < NN){
          float v = acc2[rt][r] + bias;
          store1(d_out, (size_t)n * DD + col, v, f32);
          atomicAdd(&sNagg[sGn[row] * 72 + col], v);
        }
      }
  }
  __syncthreads();
  for (int i = tid; i < NG * DD; i += 256)
    atomicAdd(&node_agg[i], sNagg[(i >> 6) * 72 + (i & 63)]);
}

__global__ __launch_bounds__(256) void global_kernel(
  const void* __restrict__ u, const float* __restrict__ node_agg, const float* __restrict__ edge_agg,
  const void* __restrict__ Wg1, const void* __restrict__ bg1,
  const void* __restrict__ Wg2, const void* __restrict__ bg2,
  void* __restrict__ d_out, const int* __restrict__ flag)
{
  __shared__ float sIn[NG * 192];
  __shared__ float sHg[NG * HH];
  const bool f32 = (*flag != 0);
  const size_t OUT_U = (size_t)NN * DD + (size_t)NE * DD;
  const int tid = threadIdx.x;
  for (int i = tid; i < NG * 192; i += 256){
    int g = i / 192, c = i - g * 192;
    float v;
    if      (c <  64) v = ldb(u, g * 64 + c, f32);
    else if (c < 128) v = node_agg[g * 64 + (c - 64)];
    else              v = edge_agg[g * 64 + (c - 128)];
    sIn[i] = v;
  }
  __syncthreads();
  for (int i = tid; i < NG * HH; i += 256){
    int g = i >> 7, j = i & 127;
    float s = ldb(bg1, j, f32);
    for (int k = 0; k < 192; ++k)
      s += sIn[g * 192 + k] * ldb(Wg1, k * 128 + j, f32);
    sHg[i] = fmaxf(s, 0.f);
  }
  __syncthreads();
  for (int i = tid; i < NG * DD; i += 256){
    int g = i >> 6, j = i & 63;
    float s = ldb(bg2, j, f32);
    for (int k = 0; k < 128; ++k)
      s += sHg[g * 128 + k] * ldb(Wg2, k * 64 + j, f32);
    store1(d_out, OUT_U + i, s, f32);
  }
}

extern "C" void kernel_launch(void* const* d_in, const int* in_sizes, int n_in,
                              void* d_out, int out_size, void* d_ws, size_t ws_size,
                              hipStream_t stream)
{
  const void* x     = d_in[0];
  const int*  ei    = (const int*)d_in[1];
  const void* e     = d_in[2];
  const void* u     = d_in[3];
  const int*  batch = (const int*)d_in[4];
  const void* We1 = d_in[5];
  const void* be1 = d_in[6];
  const void* We2 = d_in[7];
  const void* be2 = d_in[8];
  const void* Wa1 = d_in[9];
  const void* ba1 = d_in[10];
  const void* Wa2 = d_in[11];
  const void* ba2 = d_in[12];
  const void* Wn1 = d_in[13];
  const void* bn1 = d_in[14];
  const void* Wn2 = d_in[15];
  const void* bn2 = d_in[16];
  const void* Wg1 = d_in[17];
  const void* bg1 = d_in[18];
  const void* Wg2 = d_in[19];
  const void* bg2 = d_in[20];

  // workspace: [flag 16B][agg NN*DD][edge_agg][node_agg][U1][UA1][UN1][packed W]
  int*   flag     = (int*)d_ws;
  float* agg      = (float*)((char*)d_ws + 16);
  float* edge_agg = agg + (size_t)NN * DD;
  float* node_agg = edge_agg + NG * DD;
  float* U1  = node_agg + NG * DD;
  float* UA1 = U1  + NG * HH;
  float* UN1 = UA1 + NG * HH;
  u16t*  wp    = (u16t*)(UN1 + NG * HH);
  u16t*  Wp_e1 = wp; wp += 192 * 128;
  u16t*  Wp_e2 = wp; wp += 128 * 64;
  u16t*  Wp_a1 = wp; wp += 192 * 128;
  u16t*  Wp_a2 = wp; wp += 128 * 64;
  u16t*  Wp_n1 = wp; wp += 128 * 128;
  u16t*  Wp_n2 = wp; wp += 128 * 64;

  detect_kernel<<<1, 64, 0, stream>>>(x, flag);
  hipMemsetAsync(agg, 0, ((size_t)NN * DD + 2 * NG * DD) * sizeof(float), stream);

  ufold_kernel<<<(3 * NG * HH + 255) / 256, 256, 0, stream>>>(
      u, We1, be1, Wa1, ba1, Wn1, bn1, U1, UA1, UN1, flag);

  repack_kernel<<<(192 * 128 + 255) / 256, 256, 0, stream>>>(We1, Wp_e1, 192, 128, flag);
  repack_kernel<<<(128 * 64  + 255) / 256, 256, 0, stream>>>(We2, Wp_e2, 128, 64, flag);
  repack_kernel<<<(192 * 128 + 255) / 256, 256, 0, stream>>>(Wa1, Wp_a1, 192, 128, flag);
  repack_kernel<<<(128 * 64  + 255) / 256, 256, 0, stream>>>(Wa2, Wp_a2, 128, 64, flag);
  repack_kernel<<<(128 * 128 + 255) / 256, 256, 0, stream>>>(Wn1, Wp_n1, 128, 128, flag);
  repack_kernel<<<(128 * 64  + 255) / 256, 256, 0, stream>>>(Wn2, Wp_n2, 128, 64, flag);

  edge_kernel<<<1536, 256, 0, stream>>>(x, ei, e, batch,
      Wp_e1, Wp_a1, Wp_e2, be2, Wp_a2, ba2, U1, UA1,
      d_out, agg, edge_agg, flag, NE / 64);

  node_kernel<<<(NN + 63) / 64, 256, 0, stream>>>(x, agg, batch,
      Wp_n1, UN1, Wp_n2, bn2, d_out, node_agg, flag);

  global_kernel<<<1, 256, 0, stream>>>(u, node_agg, edge_agg,
      Wg1, bg1, Wg2, bg2, d_out, flag);
}